// Round 2
// baseline (716.847 us; speedup 1.0000x reference)
//
#include <hip/hip_runtime.h>

#define S_LEN 4096
#define DMODEL 1024
#define NHEADS 16
#define DHEAD 64

typedef __attribute__((ext_vector_type(8))) short bf16x8;
typedef __attribute__((ext_vector_type(4))) float f32x4;

__device__ inline unsigned short f2bf(float f) {
    union { float f; unsigned int u; } v; v.f = f;
    unsigned int r = v.u + 0x7fffu + ((v.u >> 16) & 1u);
    return (unsigned short)(r >> 16);
}

// Load 16 contiguous fp32, convert to bf16, store to LDS (16B-aligned dst).
__device__ inline void ld16f_bf(const float* __restrict__ p, unsigned short* dst) {
    const float4* q = (const float4*)p;
    float4 v0 = q[0], v1 = q[1], v2 = q[2], v3 = q[3];
    unsigned short t[16];
    t[0] = f2bf(v0.x); t[1] = f2bf(v0.y); t[2] = f2bf(v0.z); t[3] = f2bf(v0.w);
    t[4] = f2bf(v1.x); t[5] = f2bf(v1.y); t[6] = f2bf(v1.z); t[7] = f2bf(v1.w);
    t[8] = f2bf(v2.x); t[9] = f2bf(v2.y); t[10] = f2bf(v2.z); t[11] = f2bf(v2.w);
    t[12] = f2bf(v3.x); t[13] = f2bf(v3.y); t[14] = f2bf(v3.z); t[15] = f2bf(v3.w);
    *(bf16x8*)dst = *(const bf16x8*)t;
    *(bf16x8*)(dst + 8) = *(const bf16x8*)(t + 8);
}

// C = A (MxK) * B^T (B is NxK fp32). A is fp32 (A32=1) or bf16 (A32=0). fp32 accum.
// MODE 0: C fp32 row-major [M][N]
// MODE 1: C bf16 head-split [h][m][c] (h=col>>6, c=col&63), for Q,K
// MODE 2: C bf16 head-split transposed [h][c][m], for V
template <bool A32, int MODE>
__global__ __launch_bounds__(256) void gemm_nt(const void* __restrict__ Ap,
                                               const float* __restrict__ B,
                                               void* __restrict__ Cp,
                                               int M, int N, int K) {
    __shared__ __align__(16) unsigned short As[128 * 32];
    __shared__ __align__(16) unsigned short Bs[128 * 32];
    const int tid = threadIdx.x;
    const int lane = tid & 63;
    const int wave = tid >> 6;
    const int wm = (wave >> 1) * 64;
    const int wn = (wave & 1) * 64;
    const int m0 = blockIdx.y * 128;
    const int n0 = blockIdx.x * 128;
    const int l15 = lane & 15;
    const int quad = lane >> 4;

    f32x4 acc[4][4];
#pragma unroll
    for (int i = 0; i < 4; i++)
#pragma unroll
        for (int j = 0; j < 4; j++) acc[i][j] = (f32x4){0.f, 0.f, 0.f, 0.f};

    const int ldRow = tid >> 1;
    const int ldCol = (tid & 1) * 16;

    for (int kk = 0; kk < K; kk += 32) {
        __syncthreads();
        if (A32) {
            ld16f_bf((const float*)Ap + (size_t)(m0 + ldRow) * K + kk + ldCol,
                     As + ldRow * 32 + ldCol);
        } else {
            const bf16x8* ga = (const bf16x8*)((const unsigned short*)Ap +
                                               (size_t)(m0 + ldRow) * K + kk + ldCol);
            *(bf16x8*)(As + ldRow * 32 + ldCol)     = ga[0];
            *(bf16x8*)(As + ldRow * 32 + ldCol + 8) = ga[1];
        }
        ld16f_bf(B + (size_t)(n0 + ldRow) * K + kk + ldCol, Bs + ldRow * 32 + ldCol);
        __syncthreads();

        bf16x8 af[4], bfr[4];
#pragma unroll
        for (int i = 0; i < 4; i++)
            af[i] = *(const bf16x8*)(As + (wm + i * 16 + l15) * 32 + quad * 8);
#pragma unroll
        for (int j = 0; j < 4; j++)
            bfr[j] = *(const bf16x8*)(Bs + (wn + j * 16 + l15) * 32 + quad * 8);
#pragma unroll
        for (int i = 0; i < 4; i++)
#pragma unroll
            for (int j = 0; j < 4; j++)
                acc[i][j] = __builtin_amdgcn_mfma_f32_16x16x32_bf16(af[i], bfr[j], acc[i][j], 0, 0, 0);
    }

#pragma unroll
    for (int i = 0; i < 4; i++)
#pragma unroll
        for (int j = 0; j < 4; j++)
#pragma unroll
            for (int r = 0; r < 4; r++) {
                const int row = m0 + wm + i * 16 + quad * 4 + r;
                const int col = n0 + wn + j * 16 + l15;
                if (MODE == 0) {
                    ((float*)Cp)[(size_t)row * N + col] = acc[i][j][r];
                } else if (MODE == 1) {
                    const int h = col >> 6, c = col & 63;
                    ((unsigned short*)Cp)[(size_t)h * M * 64 + (size_t)row * 64 + c] = f2bf(acc[i][j][r]);
                } else {
                    const int h = col >> 6, c = col & 63;
                    ((unsigned short*)Cp)[(size_t)h * M * 64 + (size_t)c * M + row] = f2bf(acc[i][j][r]);
                }
            }
}

// Flash attention, causal. Q,K: [H][S][64] bf16. Vt: [H][64][S] bf16. Y: [S][DMODEL] bf16.
__global__ __launch_bounds__(256) void attn(const unsigned short* __restrict__ Q,
                                            const unsigned short* __restrict__ Kh,
                                            const unsigned short* __restrict__ Vt,
                                            unsigned short* __restrict__ Y) {
    __shared__ __align__(16) unsigned short P_lds[4][16][32];
    const int h = blockIdx.y;
    const int q0 = blockIdx.x * 64;
    const int tid = threadIdx.x;
    const int lane = tid & 63;
    const int wave = tid >> 6;
    const int l15 = lane & 15;
    const int quad = lane >> 4;

    const unsigned short* Qp = Q + (size_t)h * S_LEN * 64;
    const unsigned short* Kp = Kh + (size_t)h * S_LEN * 64;
    const unsigned short* Vp = Vt + (size_t)h * 64 * S_LEN;
    const int qbase = q0 + wave * 16;

    bf16x8 aq[2];
#pragma unroll
    for (int s = 0; s < 2; s++)
        aq[s] = *(const bf16x8*)(Qp + (size_t)(qbase + l15) * 64 + s * 32 + quad * 8);

    f32x4 o[4];
#pragma unroll
    for (int j = 0; j < 4; j++) o[j] = (f32x4){0.f, 0.f, 0.f, 0.f};
    float mrow[4], lrow[4];
#pragma unroll
    for (int r = 0; r < 4; r++) { mrow[r] = -1e30f; lrow[r] = 0.f; }

    const float sl = 0.125f * 1.4426950408889634f;  // 1/sqrt(64) * log2(e)
    const int nkt = q0 / 32 + 2;  // uniform across waves (covers q0+63)

    for (int kt = 0; kt < nkt; kt++) {
        const int kb = kt * 32;
        f32x4 sc[2];
#pragma unroll
        for (int t = 0; t < 2; t++) {
            const bf16x8 b0 = *(const bf16x8*)(Kp + (size_t)(kb + t * 16 + l15) * 64 + quad * 8);
            const bf16x8 b1 = *(const bf16x8*)(Kp + (size_t)(kb + t * 16 + l15) * 64 + 32 + quad * 8);
            f32x4 c = (f32x4){0.f, 0.f, 0.f, 0.f};
            c = __builtin_amdgcn_mfma_f32_16x16x32_bf16(aq[0], b0, c, 0, 0, 0);
            c = __builtin_amdgcn_mfma_f32_16x16x32_bf16(aq[1], b1, c, 0, 0, 0);
            sc[t] = c;
        }
        float mx[4];
#pragma unroll
        for (int r = 0; r < 4; r++) {
            const int qrow = qbase + quad * 4 + r;
            float v0 = sc[0][r] * sl;
            float v1 = sc[1][r] * sl;
            if (kb + l15 > qrow) v0 = -1e30f;
            if (kb + 16 + l15 > qrow) v1 = -1e30f;
            sc[0][r] = v0; sc[1][r] = v1;
            mx[r] = fmaxf(v0, v1);
        }
#pragma unroll
        for (int off = 1; off < 16; off <<= 1)
#pragma unroll
            for (int r = 0; r < 4; r++) mx[r] = fmaxf(mx[r], __shfl_xor(mx[r], off));

        float alpha[4], rs[4];
#pragma unroll
        for (int r = 0; r < 4; r++) {
            const float mn = fmaxf(mrow[r], mx[r]);
            alpha[r] = exp2f(mrow[r] - mn);
            mrow[r] = mn;
            const float p0 = exp2f(sc[0][r] - mn);
            const float p1 = exp2f(sc[1][r] - mn);
            sc[0][r] = p0; sc[1][r] = p1;
            rs[r] = p0 + p1;
        }
#pragma unroll
        for (int off = 1; off < 16; off <<= 1)
#pragma unroll
            for (int r = 0; r < 4; r++) rs[r] += __shfl_xor(rs[r], off);
#pragma unroll
        for (int r = 0; r < 4; r++) lrow[r] = lrow[r] * alpha[r] + rs[r];
#pragma unroll
        for (int j = 0; j < 4; j++)
#pragma unroll
            for (int r = 0; r < 4; r++) o[j][r] *= alpha[r];

#pragma unroll
        for (int t = 0; t < 2; t++)
#pragma unroll
            for (int r = 0; r < 4; r++)
                P_lds[wave][quad * 4 + r][t * 16 + l15] = f2bf(sc[t][r]);
        __syncthreads();

        const bf16x8 ap = *(const bf16x8*)(&P_lds[wave][l15][quad * 8]);
#pragma unroll
        for (int j = 0; j < 4; j++) {
            const bf16x8 bv = *(const bf16x8*)(Vp + (size_t)(j * 16 + l15) * S_LEN + kb + quad * 8);
            o[j] = __builtin_amdgcn_mfma_f32_16x16x32_bf16(ap, bv, o[j], 0, 0, 0);
        }
    }

#pragma unroll
    for (int j = 0; j < 4; j++)
#pragma unroll
        for (int r = 0; r < 4; r++) {
            const float v = o[j][r] / lrow[r];
            const int row = qbase + quad * 4 + r;
            Y[(size_t)row * DMODEL + h * 64 + j * 16 + l15] = f2bf(v);
        }
}

extern "C" void kernel_launch(void* const* d_in, const int* in_sizes, int n_in,
                              void* d_out, int out_size, void* d_ws, size_t ws_size,
                              hipStream_t stream) {
    const float* x  = (const float*)d_in[0];
    const float* wq = (const float*)d_in[1];
    const float* wk = (const float*)d_in[2];
    const float* wv = (const float*)d_in[3];
    const float* wo = (const float*)d_in[4];
    float* out = (float*)d_out;

    unsigned short* qh = (unsigned short*)d_ws;
    unsigned short* kh = qh + (size_t)S_LEN * DMODEL;
    unsigned short* vt = kh + (size_t)S_LEN * DMODEL;
    unsigned short* y  = vt + (size_t)S_LEN * DMODEL;

    const dim3 blk(256);
    const dim3 gg(DMODEL / 128, S_LEN / 128);  // (8, 32)

    gemm_nt<true, 1><<<gg, blk, 0, stream>>>(x, wq, qh, S_LEN, DMODEL, DMODEL);
    gemm_nt<true, 1><<<gg, blk, 0, stream>>>(x, wk, kh, S_LEN, DMODEL, DMODEL);
    gemm_nt<true, 2><<<gg, blk, 0, stream>>>(x, wv, vt, S_LEN, DMODEL, DMODEL);
    attn<<<dim3(S_LEN / 64, NHEADS), blk, 0, stream>>>(qh, kh, vt, y);
    gemm_nt<false, 0><<<gg, blk, 0, stream>>>(y, wo, out, S_LEN, DMODEL, DMODEL);
}

// Round 3
// 698.579 us; speedup vs baseline: 1.0262x; 1.0262x over previous
//
#include <hip/hip_runtime.h>

#define S_LEN 4096
#define DMODEL 1024
#define NHEADS 16
#define DHEAD 64

typedef __attribute__((ext_vector_type(8))) short bf16x8;
typedef __attribute__((ext_vector_type(4))) float f32x4;

__device__ inline unsigned short f2bf(float f) {
    union { float f; unsigned int u; } v; v.f = f;
    unsigned int r = v.u + 0x7fffu + ((v.u >> 16) & 1u);
    return (unsigned short)(r >> 16);
}

// Load 16 contiguous fp32, convert to bf16, store to LDS (16B-aligned dst).
__device__ inline void ld16f_bf(const float* __restrict__ p, unsigned short* dst) {
    const float4* q = (const float4*)p;
    float4 v0 = q[0], v1 = q[1], v2 = q[2], v3 = q[3];
    unsigned short t[16];
    t[0] = f2bf(v0.x); t[1] = f2bf(v0.y); t[2] = f2bf(v0.z); t[3] = f2bf(v0.w);
    t[4] = f2bf(v1.x); t[5] = f2bf(v1.y); t[6] = f2bf(v1.z); t[7] = f2bf(v1.w);
    t[8] = f2bf(v2.x); t[9] = f2bf(v2.y); t[10] = f2bf(v2.z); t[11] = f2bf(v2.w);
    t[12] = f2bf(v3.x); t[13] = f2bf(v3.y); t[14] = f2bf(v3.z); t[15] = f2bf(v3.w);
    *(bf16x8*)dst = *(const bf16x8*)t;
    *(bf16x8*)(dst + 8) = *(const bf16x8*)(t + 8);
}

// C = A (MxK) * B^T (B is NxK fp32). A is fp32 (A32=1) or bf16 (A32=0). fp32 accum.
// MODE 0: C fp32 row-major [M][N]
// MODE 1: C bf16 head-split [h][m][c] (h=col>>6, c=col&63), for Q,K
// MODE 2: C bf16 head-split transposed [h][c][m], for V
template <bool A32, int MODE>
__global__ __launch_bounds__(256) void gemm_nt(const void* __restrict__ Ap,
                                               const float* __restrict__ B,
                                               void* __restrict__ Cp,
                                               int M, int N, int K) {
    __shared__ __align__(16) unsigned short As[128 * 32];
    __shared__ __align__(16) unsigned short Bs[128 * 32];
    const int tid = threadIdx.x;
    const int lane = tid & 63;
    const int wave = tid >> 6;
    const int wm = (wave >> 1) * 64;
    const int wn = (wave & 1) * 64;
    const int m0 = blockIdx.y * 128;
    const int n0 = blockIdx.x * 128;
    const int l15 = lane & 15;
    const int quad = lane >> 4;

    f32x4 acc[4][4];
#pragma unroll
    for (int i = 0; i < 4; i++)
#pragma unroll
        for (int j = 0; j < 4; j++) acc[i][j] = (f32x4){0.f, 0.f, 0.f, 0.f};

    const int ldRow = tid >> 1;
    const int ldCol = (tid & 1) * 16;

    for (int kk = 0; kk < K; kk += 32) {
        __syncthreads();
        if (A32) {
            ld16f_bf((const float*)Ap + (size_t)(m0 + ldRow) * K + kk + ldCol,
                     As + ldRow * 32 + ldCol);
        } else {
            const bf16x8* ga = (const bf16x8*)((const unsigned short*)Ap +
                                               (size_t)(m0 + ldRow) * K + kk + ldCol);
            *(bf16x8*)(As + ldRow * 32 + ldCol)     = ga[0];
            *(bf16x8*)(As + ldRow * 32 + ldCol + 8) = ga[1];
        }
        ld16f_bf(B + (size_t)(n0 + ldRow) * K + kk + ldCol, Bs + ldRow * 32 + ldCol);
        __syncthreads();

        bf16x8 af[4], bfr[4];
#pragma unroll
        for (int i = 0; i < 4; i++)
            af[i] = *(const bf16x8*)(As + (wm + i * 16 + l15) * 32 + quad * 8);
#pragma unroll
        for (int j = 0; j < 4; j++)
            bfr[j] = *(const bf16x8*)(Bs + (wn + j * 16 + l15) * 32 + quad * 8);
#pragma unroll
        for (int i = 0; i < 4; i++)
#pragma unroll
            for (int j = 0; j < 4; j++)
                acc[i][j] = __builtin_amdgcn_mfma_f32_16x16x32_bf16(af[i], bfr[j], acc[i][j], 0, 0, 0);
    }

#pragma unroll
    for (int i = 0; i < 4; i++)
#pragma unroll
        for (int j = 0; j < 4; j++)
#pragma unroll
            for (int r = 0; r < 4; r++) {
                const int row = m0 + wm + i * 16 + quad * 4 + r;
                const int col = n0 + wn + j * 16 + l15;
                if (MODE == 0) {
                    ((float*)Cp)[(size_t)row * N + col] = acc[i][j][r];
                } else if (MODE == 1) {
                    const int h = col >> 6, c = col & 63;
                    ((unsigned short*)Cp)[(size_t)h * M * 64 + (size_t)row * 64 + c] = f2bf(acc[i][j][r]);
                } else {
                    const int h = col >> 6, c = col & 63;
                    ((unsigned short*)Cp)[(size_t)h * M * 64 + (size_t)c * M + row] = f2bf(acc[i][j][r]);
                }
            }
}

// Flash attention, causal, one wave per 16 Q rows of one head.
// Q,K: [H][S][64] bf16. Vt: [H][64][S] bf16. Y: [S][DMODEL] bf16.
// Unnormalized softmax (no running max: scores ~N(0,1), fp32 exp2 safe),
// deferred row-sum (one shuffle reduction at the end). No __syncthreads.
__global__ __launch_bounds__(64) void attn(const unsigned short* __restrict__ Q,
                                           const unsigned short* __restrict__ Kh,
                                           const unsigned short* __restrict__ Vt,
                                           unsigned short* __restrict__ Y) {
    __shared__ __align__(16) unsigned short P_lds[16][32];
    const int h = blockIdx.y;
    const int qw = gridDim.x - 1 - blockIdx.x;  // LPT: longest q-tiles first
    const int qbase = qw * 16;
    const int lane = threadIdx.x;
    const int l15 = lane & 15;
    const int quad = lane >> 4;

    const unsigned short* Qp = Q + (size_t)h * S_LEN * 64;
    const unsigned short* Kp = Kh + (size_t)h * S_LEN * 64;
    const unsigned short* Vp = Vt + (size_t)h * 64 * S_LEN;

    bf16x8 aq[2];
#pragma unroll
    for (int s = 0; s < 2; s++)
        aq[s] = *(const bf16x8*)(Qp + (size_t)(qbase + l15) * 64 + s * 32 + quad * 8);

    f32x4 o[4];
#pragma unroll
    for (int j = 0; j < 4; j++) o[j] = (f32x4){0.f, 0.f, 0.f, 0.f};
    float lrow[4] = {0.f, 0.f, 0.f, 0.f};

    const float sl = 0.125f * 1.4426950408889634f;  // 1/sqrt(64) * log2(e)
    const int nkt = (qbase >> 5) + 1;  // covers keys <= qbase+15

    for (int kt = 0; kt < nkt; kt++) {
        const int kb = kt * 32;
        f32x4 sc[2];
#pragma unroll
        for (int t = 0; t < 2; t++) {
            const bf16x8 b0 = *(const bf16x8*)(Kp + (size_t)(kb + t * 16 + l15) * 64 + quad * 8);
            const bf16x8 b1 = *(const bf16x8*)(Kp + (size_t)(kb + t * 16 + l15) * 64 + 32 + quad * 8);
            f32x4 c = (f32x4){0.f, 0.f, 0.f, 0.f};
            c = __builtin_amdgcn_mfma_f32_16x16x32_bf16(aq[0], b0, c, 0, 0, 0);
            c = __builtin_amdgcn_mfma_f32_16x16x32_bf16(aq[1], b1, c, 0, 0, 0);
            sc[t] = c;
        }

        float p[2][4];
        if (kt < nkt - 1) {  // interior tile: no mask
#pragma unroll
            for (int t = 0; t < 2; t++)
#pragma unroll
                for (int r = 0; r < 4; r++) p[t][r] = exp2f(sc[t][r] * sl);
        } else {  // boundary tile: causal mask
#pragma unroll
            for (int t = 0; t < 2; t++)
#pragma unroll
                for (int r = 0; r < 4; r++) {
                    const int qrow = qbase + quad * 4 + r;
                    const int col = kb + t * 16 + l15;
                    p[t][r] = (col > qrow) ? 0.f : exp2f(sc[t][r] * sl);
                }
        }
#pragma unroll
        for (int r = 0; r < 4; r++) lrow[r] += p[0][r] + p[1][r];

#pragma unroll
        for (int t = 0; t < 2; t++)
#pragma unroll
            for (int r = 0; r < 4; r++)
                P_lds[quad * 4 + r][t * 16 + l15] = f2bf(p[t][r]);
        // within-wave LDS write->read: compiler inserts lgkmcnt wait
        const bf16x8 ap = *(const bf16x8*)(&P_lds[l15][quad * 8]);
#pragma unroll
        for (int j = 0; j < 4; j++) {
            const bf16x8 bv = *(const bf16x8*)(Vp + (size_t)(j * 16 + l15) * S_LEN + kb + quad * 8);
            o[j] = __builtin_amdgcn_mfma_f32_16x16x32_bf16(ap, bv, o[j], 0, 0, 0);
        }
    }

    // one-time row-sum reduction over the 16 lanes holding each row
#pragma unroll
    for (int off = 1; off < 16; off <<= 1)
#pragma unroll
        for (int r = 0; r < 4; r++) lrow[r] += __shfl_xor(lrow[r], off);

#pragma unroll
    for (int j = 0; j < 4; j++)
#pragma unroll
        for (int r = 0; r < 4; r++) {
            const int row = qbase + quad * 4 + r;
            Y[(size_t)row * DMODEL + h * 64 + j * 16 + l15] = f2bf(o[j][r] / lrow[r]);
        }
}

extern "C" void kernel_launch(void* const* d_in, const int* in_sizes, int n_in,
                              void* d_out, int out_size, void* d_ws, size_t ws_size,
                              hipStream_t stream) {
    const float* x  = (const float*)d_in[0];
    const float* wq = (const float*)d_in[1];
    const float* wk = (const float*)d_in[2];
    const float* wv = (const float*)d_in[3];
    const float* wo = (const float*)d_in[4];
    float* out = (float*)d_out;

    unsigned short* qh = (unsigned short*)d_ws;
    unsigned short* kh = qh + (size_t)S_LEN * DMODEL;
    unsigned short* vt = kh + (size_t)S_LEN * DMODEL;
    unsigned short* y  = vt + (size_t)S_LEN * DMODEL;

    const dim3 blk(256);
    const dim3 gg(DMODEL / 128, S_LEN / 128);  // (8, 32)

    gemm_nt<true, 1><<<gg, blk, 0, stream>>>(x, wq, qh, S_LEN, DMODEL, DMODEL);
    gemm_nt<true, 1><<<gg, blk, 0, stream>>>(x, wk, kh, S_LEN, DMODEL, DMODEL);
    gemm_nt<true, 2><<<gg, blk, 0, stream>>>(x, wv, vt, S_LEN, DMODEL, DMODEL);
    attn<<<dim3(S_LEN / 16, NHEADS), dim3(64), 0, stream>>>(qh, kh, vt, y);
    gemm_nt<false, 0><<<gg, blk, 0, stream>>>(y, wo, out, S_LEN, DMODEL, DMODEL);
}

// Round 4
// 315.579 us; speedup vs baseline: 2.2715x; 2.2136x over previous
//
#include <hip/hip_runtime.h>

#define S_LEN 4096
#define DMODEL 1024
#define NHEADS 16
#define DHEAD 64

typedef __attribute__((ext_vector_type(8))) short bf16x8;
typedef __attribute__((ext_vector_type(4))) float f32x4;

__device__ inline unsigned short f2bf(float f) {
    union { float f; unsigned int u; } v; v.f = f;
    unsigned int r = v.u + 0x7fffu + ((v.u >> 16) & 1u);
    return (unsigned short)(r >> 16);
}

// async 16B global -> LDS (DMA, no VGPR roundtrip). LDS dst must be
// wave-uniform-base + lane*16 — all call sites below satisfy this.
__device__ inline void cp16(const void* g, void* l) {
    __builtin_amdgcn_global_load_lds(
        (const __attribute__((address_space(1))) unsigned int*)g,
        (__attribute__((address_space(3))) unsigned int*)l, 16, 0, 0);
}

// fp32 -> bf16 elementwise, 8 elems/thread, exact-size grid (n % 2048 == 0)
__global__ __launch_bounds__(256) void cvt_bf16(const float* __restrict__ src,
                                                unsigned short* __restrict__ dst, int n) {
    const int i = (blockIdx.x * 256 + threadIdx.x) * 8;
    const float4 a = *(const float4*)(src + i);
    const float4 b = *(const float4*)(src + i + 4);
    unsigned short t[8];
    t[0] = f2bf(a.x); t[1] = f2bf(a.y); t[2] = f2bf(a.z); t[3] = f2bf(a.w);
    t[4] = f2bf(b.x); t[5] = f2bf(b.y); t[6] = f2bf(b.z); t[7] = f2bf(b.w);
    *(bf16x8*)(dst + i) = *(const bf16x8*)t;
}

// C = A (MxK bf16) * B^T (B NxK bf16). m97-style: global_load_lds staging.
// MODE 0: C fp32 [M][N]; MODE 1: C bf16 [h][m][c]; MODE 2: C bf16 [h][c][m]
template <int MODE>
__global__ __launch_bounds__(256) void gemm_nt(const unsigned short* __restrict__ A,
                                               const unsigned short* __restrict__ B,
                                               void* __restrict__ Cp,
                                               int M, int N, int K) {
    __shared__ __align__(16) unsigned short As[128 * 32];
    __shared__ __align__(16) unsigned short Bs[128 * 32];
    const int tid = threadIdx.x;
    const int lane = tid & 63;
    const int wave = tid >> 6;
    const int wm = (wave >> 1) * 64;
    const int wn = (wave & 1) * 64;
    const int m0 = blockIdx.y * 128;
    const int n0 = blockIdx.x * 128;
    const int l15 = lane & 15;
    const int quad = lane >> 4;

    f32x4 acc[4][4];
#pragma unroll
    for (int i = 0; i < 4; i++)
#pragma unroll
        for (int j = 0; j < 4; j++) acc[i][j] = (f32x4){0.f, 0.f, 0.f, 0.f};

    const int r0 = tid >> 2;        // 0..63
    const int c0 = (tid & 3) * 8;   // 0,8,16,24

    for (int kk = 0; kk < K; kk += 32) {
        __syncthreads();
        cp16(A + (size_t)(m0 + r0) * K + kk + c0,      As + r0 * 32 + c0);
        cp16(A + (size_t)(m0 + r0 + 64) * K + kk + c0, As + (r0 + 64) * 32 + c0);
        cp16(B + (size_t)(n0 + r0) * K + kk + c0,      Bs + r0 * 32 + c0);
        cp16(B + (size_t)(n0 + r0 + 64) * K + kk + c0, Bs + (r0 + 64) * 32 + c0);
        __syncthreads();  // drains vmcnt(0): staged data visible

        bf16x8 af[4], bfr[4];
#pragma unroll
        for (int i = 0; i < 4; i++)
            af[i] = *(const bf16x8*)(As + (wm + i * 16 + l15) * 32 + quad * 8);
#pragma unroll
        for (int j = 0; j < 4; j++)
            bfr[j] = *(const bf16x8*)(Bs + (wn + j * 16 + l15) * 32 + quad * 8);
#pragma unroll
        for (int i = 0; i < 4; i++)
#pragma unroll
            for (int j = 0; j < 4; j++)
                acc[i][j] = __builtin_amdgcn_mfma_f32_16x16x32_bf16(af[i], bfr[j], acc[i][j], 0, 0, 0);
    }

#pragma unroll
    for (int i = 0; i < 4; i++)
#pragma unroll
        for (int j = 0; j < 4; j++)
#pragma unroll
            for (int r = 0; r < 4; r++) {
                const int row = m0 + wm + i * 16 + quad * 4 + r;
                const int col = n0 + wn + j * 16 + l15;
                if (MODE == 0) {
                    ((float*)Cp)[(size_t)row * N + col] = acc[i][j][r];
                } else if (MODE == 1) {
                    const int h = col >> 6, c = col & 63;
                    ((unsigned short*)Cp)[(size_t)h * M * 64 + (size_t)row * 64 + c] = f2bf(acc[i][j][r]);
                } else {
                    const int h = col >> 6, c = col & 63;
                    ((unsigned short*)Cp)[(size_t)h * M * 64 + (size_t)c * M + row] = f2bf(acc[i][j][r]);
                }
            }
}

// Flash attention, causal. Block = 4 waves; processes TWO mirrored 64-row
// q-tiles (qa=64*b and qa=S-64*(b+1)) -> every block does exactly 65
// 64-key tiles (perfect balance). K/V tiles staged to LDS via
// global_load_lds, shared by all 4 waves. Unnormalized softmax.
__global__ __launch_bounds__(256) void attn(const unsigned short* __restrict__ Q,
                                            const unsigned short* __restrict__ Kh,
                                            const unsigned short* __restrict__ Vt,
                                            unsigned short* __restrict__ Y) {
    __shared__ __align__(16) unsigned short Ks[64 * 64];   // [key][dim]
    __shared__ __align__(16) unsigned short Vs[64 * 64];   // [dim][key]
    __shared__ __align__(16) unsigned short Pl[4][16 * 64];
    const int h = blockIdx.y;
    const int bx = blockIdx.x;
    const int tid = threadIdx.x;
    const int lane = tid & 63;
    const int w = tid >> 6;
    const int l15 = lane & 15;
    const int quad = lane >> 4;

    const unsigned short* Qp = Q + (size_t)h * S_LEN * 64;
    const unsigned short* Kp = Kh + (size_t)h * S_LEN * 64;
    const unsigned short* Vp = Vt + (size_t)h * 64 * S_LEN;

    const float sl = 0.125f * 1.4426950408889634f;  // 1/sqrt(64) * log2(e)

    for (int half = 0; half < 2; half++) {
        const int qa = (half == 0) ? 64 * bx : S_LEN - 64 * (bx + 1);
        const int nkt = (qa >> 6) + 1;
        const int qbase = qa + w * 16;

        bf16x8 aq[2];
#pragma unroll
        for (int s = 0; s < 2; s++)
            aq[s] = *(const bf16x8*)(Qp + (size_t)(qbase + l15) * 64 + s * 32 + quad * 8);

        f32x4 o[4];
#pragma unroll
        for (int j = 0; j < 4; j++) o[j] = (f32x4){0.f, 0.f, 0.f, 0.f};
        float lrow[4] = {0.f, 0.f, 0.f, 0.f};

        for (int kt = 0; kt < nkt; kt++) {
            const int kb = kt * 64;
            __syncthreads();  // previous tile's LDS reads complete
            // K tile: 8KB contiguous in global
            cp16(Kp + (size_t)kb * 64 + tid * 8,        Ks + tid * 8);
            cp16(Kp + (size_t)kb * 64 + tid * 8 + 2048, Ks + tid * 8 + 2048);
            // V tile: 64 dims x 64 keys from Vt[dim][S]
            cp16(Vp + (size_t)(tid >> 3) * S_LEN + kb + (tid & 7) * 8,        Vs + tid * 8);
            cp16(Vp + (size_t)((tid >> 3) + 32) * S_LEN + kb + (tid & 7) * 8, Vs + tid * 8 + 2048);
            __syncthreads();  // drains vmcnt(0)

            float p[4][4];
            const bool boundary = (kt == nkt - 1);
#pragma unroll
            for (int t = 0; t < 4; t++) {
                const bf16x8 b0 = *(const bf16x8*)(Ks + (t * 16 + l15) * 64 + quad * 8);
                const bf16x8 b1 = *(const bf16x8*)(Ks + (t * 16 + l15) * 64 + 32 + quad * 8);
                f32x4 c = (f32x4){0.f, 0.f, 0.f, 0.f};
                c = __builtin_amdgcn_mfma_f32_16x16x32_bf16(aq[0], b0, c, 0, 0, 0);
                c = __builtin_amdgcn_mfma_f32_16x16x32_bf16(aq[1], b1, c, 0, 0, 0);
                if (boundary) {
#pragma unroll
                    for (int r = 0; r < 4; r++) {
                        const int qrow = qbase + quad * 4 + r;
                        const int col = kb + t * 16 + l15;
                        p[t][r] = (col > qrow) ? 0.f : exp2f(c[r] * sl);
                    }
                } else {
#pragma unroll
                    for (int r = 0; r < 4; r++) p[t][r] = exp2f(c[r] * sl);
                }
            }
#pragma unroll
            for (int r = 0; r < 4; r++)
                lrow[r] += (p[0][r] + p[1][r]) + (p[2][r] + p[3][r]);

            // P: C-layout -> LDS -> A-layout (per-wave private region)
#pragma unroll
            for (int t = 0; t < 4; t++)
#pragma unroll
                for (int r = 0; r < 4; r++)
                    Pl[w][(quad * 4 + r) * 64 + t * 16 + l15] = f2bf(p[t][r]);
            const bf16x8 ap0 = *(const bf16x8*)(&Pl[w][l15 * 64 + quad * 8]);
            const bf16x8 ap1 = *(const bf16x8*)(&Pl[w][l15 * 64 + 32 + quad * 8]);
#pragma unroll
            for (int j = 0; j < 4; j++) {
                const bf16x8 v0 = *(const bf16x8*)(Vs + (j * 16 + l15) * 64 + quad * 8);
                const bf16x8 v1 = *(const bf16x8*)(Vs + (j * 16 + l15) * 64 + 32 + quad * 8);
                o[j] = __builtin_amdgcn_mfma_f32_16x16x32_bf16(ap0, v0, o[j], 0, 0, 0);
                o[j] = __builtin_amdgcn_mfma_f32_16x16x32_bf16(ap1, v1, o[j], 0, 0, 0);
            }
        }

#pragma unroll
        for (int off = 1; off < 16; off <<= 1)
#pragma unroll
            for (int r = 0; r < 4; r++) lrow[r] += __shfl_xor(lrow[r], off);

#pragma unroll
        for (int j = 0; j < 4; j++)
#pragma unroll
            for (int r = 0; r < 4; r++) {
                const int row = qbase + quad * 4 + r;
                Y[(size_t)row * DMODEL + h * 64 + j * 16 + l15] = f2bf(o[j][r] / lrow[r]);
            }
    }
}

extern "C" void kernel_launch(void* const* d_in, const int* in_sizes, int n_in,
                              void* d_out, int out_size, void* d_ws, size_t ws_size,
                              hipStream_t stream) {
    const float* x  = (const float*)d_in[0];
    const float* wq = (const float*)d_in[1];
    const float* wk = (const float*)d_in[2];
    const float* wv = (const float*)d_in[3];
    const float* wo = (const float*)d_in[4];
    float* out = (float*)d_out;

    // ws layout (34 MB): qh, kh, vt (8 MB each), xb/y shared slot (8 MB),
    // single 2 MB weight slot reused for each projection.
    unsigned short* qh = (unsigned short*)d_ws;
    unsigned short* kh = qh + (size_t)S_LEN * DMODEL;
    unsigned short* vt = kh + (size_t)S_LEN * DMODEL;
    unsigned short* xb = vt + (size_t)S_LEN * DMODEL;  // x bf16; later reused as y
    unsigned short* y  = xb;                            // alias: x dead after V proj
    unsigned short* wb = xb + (size_t)S_LEN * DMODEL;  // 2 MB weight slot

    const dim3 blk(256);
    const dim3 gg(DMODEL / 128, S_LEN / 128);  // (8, 32)
    const int nx = S_LEN * DMODEL;      // 4M
    const int nw = DMODEL * DMODEL;     // 1M

    cvt_bf16<<<nx / 2048, blk, 0, stream>>>(x, xb, nx);
    cvt_bf16<<<nw / 2048, blk, 0, stream>>>(wq, wb, nw);
    gemm_nt<1><<<gg, blk, 0, stream>>>(xb, wb, qh, S_LEN, DMODEL, DMODEL);
    cvt_bf16<<<nw / 2048, blk, 0, stream>>>(wk, wb, nw);
    gemm_nt<1><<<gg, blk, 0, stream>>>(xb, wb, kh, S_LEN, DMODEL, DMODEL);
    cvt_bf16<<<nw / 2048, blk, 0, stream>>>(wv, wb, nw);
    gemm_nt<2><<<gg, blk, 0, stream>>>(xb, wb, vt, S_LEN, DMODEL, DMODEL);
    attn<<<dim3(S_LEN / 128, NHEADS), blk, 0, stream>>>(qh, kh, vt, y);
    cvt_bf16<<<nw / 2048, blk, 0, stream>>>(wo, wb, nw);
    gemm_nt<0><<<gg, blk, 0, stream>>>(y, wb, out, S_LEN, DMODEL, DMODEL);
}

// Round 5
// 289.995 us; speedup vs baseline: 2.4719x; 1.0882x over previous
//
#include <hip/hip_runtime.h>

#define S_LEN 4096
#define DMODEL 1024
#define NHEADS 16

typedef __attribute__((ext_vector_type(8))) short bf16x8;
typedef __attribute__((ext_vector_type(4))) float f32x4;
typedef unsigned short u16;
typedef unsigned long long u64;

__device__ inline u16 f2bf(float f) {
    union { float f; unsigned int u; } v; v.f = f;
    unsigned int r = v.u + 0x7fffu + ((v.u >> 16) & 1u);
    return (u16)(r >> 16);
}

// async 16B global->LDS DMA. LDS dst = wave-uniform base + lane*16 at all sites.
__device__ inline void cp16(const void* g, void* l) {
    __builtin_amdgcn_global_load_lds(
        (const __attribute__((address_space(1))) unsigned int*)g,
        (__attribute__((address_space(3))) unsigned int*)l, 16, 0, 0);
}

__global__ __launch_bounds__(256) void cvt_bf16(const float* __restrict__ src,
                                                u16* __restrict__ dst, int n) {
    const int i = (blockIdx.x * 256 + threadIdx.x) * 8;
    const float4 a = *(const float4*)(src + i);
    const float4 b = *(const float4*)(src + i + 4);
    u16 t[8];
    t[0] = f2bf(a.x); t[1] = f2bf(a.y); t[2] = f2bf(a.z); t[3] = f2bf(a.w);
    t[4] = f2bf(b.x); t[5] = f2bf(b.y); t[6] = f2bf(b.z); t[7] = f2bf(b.w);
    *(bf16x8*)(dst + i) = *(const bf16x8*)t;
}

// three weights -> contiguous bf16 buffer (blockIdx.y selects source)
__global__ __launch_bounds__(256) void cvt3_bf16(const float* __restrict__ s0,
                                                 const float* __restrict__ s1,
                                                 const float* __restrict__ s2,
                                                 u16* __restrict__ dst, int n) {
    const float* s = (blockIdx.y == 0) ? s0 : (blockIdx.y == 1) ? s1 : s2;
    u16* d = dst + (size_t)blockIdx.y * n;
    const int i = (blockIdx.x * 256 + threadIdx.x) * 8;
    const float4 a = *(const float4*)(s + i);
    const float4 b = *(const float4*)(s + i + 4);
    u16 t[8];
    t[0] = f2bf(a.x); t[1] = f2bf(a.y); t[2] = f2bf(a.z); t[3] = f2bf(a.w);
    t[4] = f2bf(b.x); t[5] = f2bf(b.y); t[6] = f2bf(b.z); t[7] = f2bf(b.w);
    *(bf16x8*)(d + i) = *(const bf16x8*)t;
}

// Fused QKV projection: C = x(4096x1024) * W3^T (W3 = [wq;wk;wv] 3072x1024).
// Block's n0 selects Q/K/V output. Q,K -> [h][m][c] bf16; V -> [h][c][m] bf16.
__global__ __launch_bounds__(256) void gemm_qkv(const u16* __restrict__ A,
                                                const u16* __restrict__ B3,
                                                u16* __restrict__ Qo,
                                                u16* __restrict__ Ko,
                                                u16* __restrict__ Vo) {
    __shared__ __align__(16) u16 As[128 * 32];
    __shared__ __align__(16) u16 Bs[128 * 32];
    const int tid = threadIdx.x, lane = tid & 63, wave = tid >> 6;
    const int wm = (wave >> 1) * 64, wn = (wave & 1) * 64;
    const int m0 = blockIdx.y * 128, n0 = blockIdx.x * 128;
    const int l15 = lane & 15, quad = lane >> 4;

    f32x4 acc[4][4];
#pragma unroll
    for (int i = 0; i < 4; i++)
#pragma unroll
        for (int j = 0; j < 4; j++) acc[i][j] = (f32x4){0.f, 0.f, 0.f, 0.f};

    const int r0 = tid >> 2, c0 = (tid & 3) * 8;

    for (int kk = 0; kk < 1024; kk += 32) {
        __syncthreads();
        cp16(A + (size_t)(m0 + r0) * 1024 + kk + c0,       As + r0 * 32 + c0);
        cp16(A + (size_t)(m0 + r0 + 64) * 1024 + kk + c0,  As + (r0 + 64) * 32 + c0);
        cp16(B3 + (size_t)(n0 + r0) * 1024 + kk + c0,      Bs + r0 * 32 + c0);
        cp16(B3 + (size_t)(n0 + r0 + 64) * 1024 + kk + c0, Bs + (r0 + 64) * 32 + c0);
        __syncthreads();

        bf16x8 af[4], bfr[4];
#pragma unroll
        for (int i = 0; i < 4; i++)
            af[i] = *(const bf16x8*)(As + (wm + i * 16 + l15) * 32 + quad * 8);
#pragma unroll
        for (int j = 0; j < 4; j++)
            bfr[j] = *(const bf16x8*)(Bs + (wn + j * 16 + l15) * 32 + quad * 8);
#pragma unroll
        for (int i = 0; i < 4; i++)
#pragma unroll
            for (int j = 0; j < 4; j++)
                acc[i][j] = __builtin_amdgcn_mfma_f32_16x16x32_bf16(af[i], bfr[j], acc[i][j], 0, 0, 0);
    }

    const int which = n0 >> 10;
    const int n0r = n0 & 1023;
    u16* dst = (which == 0) ? Qo : (which == 1) ? Ko : Vo;
#pragma unroll
    for (int i = 0; i < 4; i++)
#pragma unroll
        for (int j = 0; j < 4; j++)
#pragma unroll
            for (int r = 0; r < 4; r++) {
                const int row = m0 + wm + i * 16 + quad * 4 + r;
                const int col = n0r + wn + j * 16 + l15;
                const int h = col >> 6, c = col & 63;
                const u16 v = f2bf(acc[i][j][r]);
                if (which < 2) dst[(size_t)h * S_LEN * 64 + (size_t)row * 64 + c] = v;
                else           dst[(size_t)h * S_LEN * 64 + (size_t)c * S_LEN + row] = v;
            }
}

// Output projection with split-K=2: C(fp32, pre-zeroed) += y(bf16) * wo^T.
__global__ __launch_bounds__(256) void gemm_out(const u16* __restrict__ A,
                                                const u16* __restrict__ B,
                                                float* __restrict__ C) {
    __shared__ __align__(16) u16 As[128 * 32];
    __shared__ __align__(16) u16 Bs[128 * 32];
    const int tid = threadIdx.x, lane = tid & 63, wave = tid >> 6;
    const int wm = (wave >> 1) * 64, wn = (wave & 1) * 64;
    const int m0 = blockIdx.y * 128, n0 = blockIdx.x * 128;
    const int kBeg = blockIdx.z * 512;
    const int l15 = lane & 15, quad = lane >> 4;

    f32x4 acc[4][4];
#pragma unroll
    for (int i = 0; i < 4; i++)
#pragma unroll
        for (int j = 0; j < 4; j++) acc[i][j] = (f32x4){0.f, 0.f, 0.f, 0.f};

    const int r0 = tid >> 2, c0 = (tid & 3) * 8;

    for (int kk = kBeg; kk < kBeg + 512; kk += 32) {
        __syncthreads();
        cp16(A + (size_t)(m0 + r0) * 1024 + kk + c0,      As + r0 * 32 + c0);
        cp16(A + (size_t)(m0 + r0 + 64) * 1024 + kk + c0, As + (r0 + 64) * 32 + c0);
        cp16(B + (size_t)(n0 + r0) * 1024 + kk + c0,      Bs + r0 * 32 + c0);
        cp16(B + (size_t)(n0 + r0 + 64) * 1024 + kk + c0, Bs + (r0 + 64) * 32 + c0);
        __syncthreads();

        bf16x8 af[4], bfr[4];
#pragma unroll
        for (int i = 0; i < 4; i++)
            af[i] = *(const bf16x8*)(As + (wm + i * 16 + l15) * 32 + quad * 8);
#pragma unroll
        for (int j = 0; j < 4; j++)
            bfr[j] = *(const bf16x8*)(Bs + (wn + j * 16 + l15) * 32 + quad * 8);
#pragma unroll
        for (int i = 0; i < 4; i++)
#pragma unroll
            for (int j = 0; j < 4; j++)
                acc[i][j] = __builtin_amdgcn_mfma_f32_16x16x32_bf16(af[i], bfr[j], acc[i][j], 0, 0, 0);
    }

#pragma unroll
    for (int i = 0; i < 4; i++)
#pragma unroll
        for (int j = 0; j < 4; j++)
#pragma unroll
            for (int r = 0; r < 4; r++) {
                const int row = m0 + wm + i * 16 + quad * 4 + r;
                const int col = n0 + wn + j * 16 + l15;
                atomicAdd(&C[(size_t)row * 1024 + col], acc[i][j][r]);
            }
}

// Flash attention, causal, S^T formulation + XOR-swizzled LDS.
// Q,K: [H][S][64] bf16. Vt: [H][64][S] bf16. Y: [S][DMODEL] bf16.
// Block = 4 waves, two mirrored 64-row q-tiles -> exactly 65 key-tiles/block.
__global__ __launch_bounds__(256) void attn(const u16* __restrict__ Q,
                                            const u16* __restrict__ Kh,
                                            const u16* __restrict__ Vt,
                                            u16* __restrict__ Y) {
    __shared__ __align__(16) u16 Ks[64 * 64];     // swizzled [key][dim]
    __shared__ __align__(16) u16 Vs[64 * 64];     // swizzled [dim][key]
    __shared__ __align__(16) u16 Pl[4][16 * 72];  // [q][key], stride 72
    const int h = blockIdx.y, bx = blockIdx.x;
    const int tid = threadIdx.x, lane = tid & 63, w = tid >> 6;
    const int l15 = lane & 15, quad = lane >> 4;
    const int swz = l15 & 7;

    const u16* Qp = Q + (size_t)h * S_LEN * 64;
    const u16* Kp = Kh + (size_t)h * S_LEN * 64;
    const u16* Vp = Vt + (size_t)h * 64 * S_LEN;

    // staging: lane tid owns LDS chunk tid*8; inverse-swizzle the global col
    const int srow = tid >> 3;
    const int scol = ((tid & 7) ^ (srow & 7)) * 8;

    const float sl = 0.125f * 1.4426950408889634f;  // 1/sqrt(64) * log2(e)

    for (int half = 0; half < 2; half++) {
        const int qa = (half == 0) ? 64 * bx : S_LEN - 64 * (bx + 1);
        const int nkt = (qa >> 6) + 1;
        const int qbase = qa + w * 16;
        const int qrow = qbase + l15;

        bf16x8 aq[2];
#pragma unroll
        for (int s = 0; s < 2; s++)
            aq[s] = *(const bf16x8*)(Qp + (size_t)(qbase + l15) * 64 + s * 32 + quad * 8);

        f32x4 o[4];
#pragma unroll
        for (int j = 0; j < 4; j++) o[j] = (f32x4){0.f, 0.f, 0.f, 0.f};
        float lrow = 0.f;

        for (int kt = 0; kt < nkt; kt++) {
            const int kb = kt * 64;
            __syncthreads();  // prior tile's LDS reads done
            cp16(Kp + (size_t)(kb + srow) * 64 + scol,      Ks + tid * 8);
            cp16(Kp + (size_t)(kb + srow + 32) * 64 + scol, Ks + tid * 8 + 2048);
            cp16(Vp + (size_t)srow * S_LEN + kb + scol,        Vs + tid * 8);
            cp16(Vp + (size_t)(srow + 32) * S_LEN + kb + scol, Vs + tid * 8 + 2048);
            __syncthreads();  // drains vmcnt(0): staged data visible

            const bool boundary = (kt == nkt - 1);
#pragma unroll
            for (int t = 0; t < 4; t++) {
                // A-frag = K rows (m=key), swizzled read: all 32 banks
                const bf16x8 k0 = *(const bf16x8*)(Ks + (t * 16 + l15) * 64 + (quad ^ swz) * 8);
                const bf16x8 k1 = *(const bf16x8*)(Ks + (t * 16 + l15) * 64 + ((4 + quad) ^ swz) * 8);
                f32x4 c = (f32x4){0.f, 0.f, 0.f, 0.f};
                c = __builtin_amdgcn_mfma_f32_16x16x32_bf16(k0, aq[0], c, 0, 0, 0);
                c = __builtin_amdgcn_mfma_f32_16x16x32_bf16(k1, aq[1], c, 0, 0, 0);
                // S^T: lane holds keys kb+t*16+quad*4+r for q=qrow
                const int keyb = kb + t * 16 + quad * 4;
                u16 t4[4];
                float ps = 0.f;
#pragma unroll
                for (int r = 0; r < 4; r++) {
                    float p = exp2f(c[r] * sl);
                    if (boundary && (keyb + r > qrow)) p = 0.f;
                    ps += p;
                    t4[r] = f2bf(p);
                }
                lrow += ps;
                *(u64*)(&Pl[w][l15 * 72 + t * 16 + quad * 4]) = *(const u64*)t4;
            }
            // B-frag = P rows (n=q), contiguous 16B; stride 72 -> conflict-free
            const bf16x8 p0 = *(const bf16x8*)(&Pl[w][l15 * 72 + quad * 8]);
            const bf16x8 p1 = *(const bf16x8*)(&Pl[w][l15 * 72 + 32 + quad * 8]);
#pragma unroll
            for (int jj = 0; jj < 4; jj++) {
                // A-frag = Vt rows (m=dim), swizzled
                const bf16x8 v0 = *(const bf16x8*)(Vs + (jj * 16 + l15) * 64 + (quad ^ swz) * 8);
                const bf16x8 v1 = *(const bf16x8*)(Vs + (jj * 16 + l15) * 64 + ((4 + quad) ^ swz) * 8);
                o[jj] = __builtin_amdgcn_mfma_f32_16x16x32_bf16(v0, p0, o[jj], 0, 0, 0);
                o[jj] = __builtin_amdgcn_mfma_f32_16x16x32_bf16(v1, p1, o[jj], 0, 0, 0);
            }
        }

        // O^T layout: lane owns row q=qrow, dims jj*16+quad*4+r.
        lrow += __shfl_xor(lrow, 16);
        lrow += __shfl_xor(lrow, 32);
        const float inv = 1.f / lrow;
#pragma unroll
        for (int jj = 0; jj < 4; jj++) {
            u16 t4[4];
#pragma unroll
            for (int r = 0; r < 4; r++) t4[r] = f2bf(o[jj][r] * inv);
            *(u64*)(Y + (size_t)qrow * DMODEL + h * 64 + jj * 16 + quad * 4) = *(const u64*)t4;
        }
    }
}

extern "C" void kernel_launch(void* const* d_in, const int* in_sizes, int n_in,
                              void* d_out, int out_size, void* d_ws, size_t ws_size,
                              hipStream_t stream) {
    const float* x  = (const float*)d_in[0];
    const float* wq = (const float*)d_in[1];
    const float* wk = (const float*)d_in[2];
    const float* wv = (const float*)d_in[3];
    const float* wo = (const float*)d_in[4];
    float* out = (float*)d_out;

    u16* qh  = (u16*)d_ws;                            // 8 MB
    u16* kh  = qh + (size_t)S_LEN * DMODEL;           // 8 MB
    u16* vt  = kh + (size_t)S_LEN * DMODEL;           // 8 MB
    u16* xb  = vt + (size_t)S_LEN * DMODEL;           // 8 MB (x bf16, later y)
    u16* y   = xb;                                    // alias after QKV proj
    u16* wb3 = xb + (size_t)S_LEN * DMODEL;           // 6 MB ([wq;wk;wv], later wo)

    const dim3 blk(256);
    const int nx = S_LEN * DMODEL;   // 4M
    const int nw = DMODEL * DMODEL;  // 1M

    cvt_bf16<<<nx / 2048, blk, 0, stream>>>(x, xb, nx);
    cvt3_bf16<<<dim3(nw / 2048, 3), blk, 0, stream>>>(wq, wk, wv, wb3, nw);
    gemm_qkv<<<dim3(3 * DMODEL / 128, S_LEN / 128), blk, 0, stream>>>(xb, wb3, qh, kh, vt);
    attn<<<dim3(S_LEN / 128, NHEADS), blk, 0, stream>>>(qh, kh, vt, y);
    cvt_bf16<<<nw / 2048, blk, 0, stream>>>(wo, wb3, nw);
    hipMemsetAsync(out, 0, (size_t)S_LEN * DMODEL * sizeof(float), stream);
    gemm_out<<<dim3(DMODEL / 128, S_LEN / 128, 2), blk, 0, stream>>>(y, wb3, out);
}

// Round 6
// 262.029 us; speedup vs baseline: 2.7358x; 1.1067x over previous
//
#include <hip/hip_runtime.h>

#define S_LEN 4096
#define DMODEL 1024
#define NHEADS 16

typedef __attribute__((ext_vector_type(8))) short bf16x8;
typedef __attribute__((ext_vector_type(4))) float f32x4;
typedef unsigned short u16;
typedef unsigned int u32;
typedef unsigned long long u64;

__device__ inline u16 f2bf(float f) {
    union { float f; u32 u; } v; v.f = f;
    u32 r = v.u + 0x7fffu + ((v.u >> 16) & 1u);
    return (u16)(r >> 16);
}

// pack two fp32 -> two bf16 (RNE) in one u32 via v_perm_b32. low16 = a.
__device__ inline u32 pkbf2(float a, float b) {
    union { float f; u32 u; } ua, ub; ua.f = a; ub.f = b;
    const u32 ra = ua.u + 0x7fffu + ((ua.u >> 16) & 1u);
    const u32 rb = ub.u + 0x7fffu + ((ub.u >> 16) & 1u);
    return __builtin_amdgcn_perm(rb, ra, 0x07060302u);
}

// async 16B global->LDS DMA. LDS dst = wave-uniform base + lane*16 at all sites.
__device__ inline void cp16(const void* g, void* l) {
    __builtin_amdgcn_global_load_lds(
        (const __attribute__((address_space(1))) unsigned int*)g,
        (__attribute__((address_space(3))) unsigned int*)l, 16, 0, 0);
}

__global__ __launch_bounds__(256) void cvt_bf16(const float* __restrict__ src,
                                                u16* __restrict__ dst, int n) {
    const int i = (blockIdx.x * 256 + threadIdx.x) * 8;
    const float4 a = *(const float4*)(src + i);
    const float4 b = *(const float4*)(src + i + 4);
    u16 t[8];
    t[0] = f2bf(a.x); t[1] = f2bf(a.y); t[2] = f2bf(a.z); t[3] = f2bf(a.w);
    t[4] = f2bf(b.x); t[5] = f2bf(b.y); t[6] = f2bf(b.z); t[7] = f2bf(b.w);
    *(bf16x8*)(dst + i) = *(const bf16x8*)t;
}

__global__ __launch_bounds__(256) void cvt3_bf16(const float* __restrict__ s0,
                                                 const float* __restrict__ s1,
                                                 const float* __restrict__ s2,
                                                 u16* __restrict__ dst, int n) {
    const float* s = (blockIdx.y == 0) ? s0 : (blockIdx.y == 1) ? s1 : s2;
    u16* d = dst + (size_t)blockIdx.y * n;
    const int i = (blockIdx.x * 256 + threadIdx.x) * 8;
    const float4 a = *(const float4*)(s + i);
    const float4 b = *(const float4*)(s + i + 4);
    u16 t[8];
    t[0] = f2bf(a.x); t[1] = f2bf(a.y); t[2] = f2bf(a.z); t[3] = f2bf(a.w);
    t[4] = f2bf(b.x); t[5] = f2bf(b.y); t[6] = f2bf(b.z); t[7] = f2bf(b.w);
    *(bf16x8*)(d + i) = *(const bf16x8*)t;
}

// Fused QKV projection: C = x(4096x1024) * W3^T (W3 = [wq;wk;wv] 3072x1024).
// Q is pre-scaled by 1/sqrt(64)*log2(e). Q,K -> [h][m][c]; V -> [h][c][m].
__global__ __launch_bounds__(256) void gemm_qkv(const u16* __restrict__ A,
                                                const u16* __restrict__ B3,
                                                u16* __restrict__ Qo,
                                                u16* __restrict__ Ko,
                                                u16* __restrict__ Vo) {
    __shared__ __align__(16) u16 As[128 * 32];
    __shared__ __align__(16) u16 Bs[128 * 32];
    const int tid = threadIdx.x, lane = tid & 63, wave = tid >> 6;
    const int wm = (wave >> 1) * 64, wn = (wave & 1) * 64;
    const int m0 = blockIdx.y * 128, n0 = blockIdx.x * 128;
    const int l15 = lane & 15, quad = lane >> 4;

    f32x4 acc[4][4];
#pragma unroll
    for (int i = 0; i < 4; i++)
#pragma unroll
        for (int j = 0; j < 4; j++) acc[i][j] = (f32x4){0.f, 0.f, 0.f, 0.f};

    const int r0 = tid >> 2, c0 = (tid & 3) * 8;

    for (int kk = 0; kk < 1024; kk += 32) {
        __syncthreads();
        cp16(A + (size_t)(m0 + r0) * 1024 + kk + c0,       As + r0 * 32 + c0);
        cp16(A + (size_t)(m0 + r0 + 64) * 1024 + kk + c0,  As + (r0 + 64) * 32 + c0);
        cp16(B3 + (size_t)(n0 + r0) * 1024 + kk + c0,      Bs + r0 * 32 + c0);
        cp16(B3 + (size_t)(n0 + r0 + 64) * 1024 + kk + c0, Bs + (r0 + 64) * 32 + c0);
        __syncthreads();

        bf16x8 af[4], bfr[4];
#pragma unroll
        for (int i = 0; i < 4; i++)
            af[i] = *(const bf16x8*)(As + (wm + i * 16 + l15) * 32 + quad * 8);
#pragma unroll
        for (int j = 0; j < 4; j++)
            bfr[j] = *(const bf16x8*)(Bs + (wn + j * 16 + l15) * 32 + quad * 8);
#pragma unroll
        for (int i = 0; i < 4; i++)
#pragma unroll
            for (int j = 0; j < 4; j++)
                acc[i][j] = __builtin_amdgcn_mfma_f32_16x16x32_bf16(af[i], bfr[j], acc[i][j], 0, 0, 0);
    }

    const int which = n0 >> 10;
    const int n0r = n0 & 1023;
    u16* dst = (which == 0) ? Qo : (which == 1) ? Ko : Vo;
    const float sc = (which == 0) ? 0.125f * 1.4426950408889634f : 1.0f;
#pragma unroll
    for (int i = 0; i < 4; i++)
#pragma unroll
        for (int j = 0; j < 4; j++)
#pragma unroll
            for (int r = 0; r < 4; r++) {
                const int row = m0 + wm + i * 16 + quad * 4 + r;
                const int col = n0r + wn + j * 16 + l15;
                const int h = col >> 6, c = col & 63;
                const u16 v = f2bf(acc[i][j][r] * sc);
                if (which < 2) dst[(size_t)h * S_LEN * 64 + (size_t)row * 64 + c] = v;
                else           dst[(size_t)h * S_LEN * 64 + (size_t)c * S_LEN + row] = v;
            }
}

// Output projection with split-K=2: C(fp32, pre-zeroed) += y(bf16) * wo^T.
__global__ __launch_bounds__(256) void gemm_out(const u16* __restrict__ A,
                                                const u16* __restrict__ B,
                                                float* __restrict__ C) {
    __shared__ __align__(16) u16 As[128 * 32];
    __shared__ __align__(16) u16 Bs[128 * 32];
    const int tid = threadIdx.x, lane = tid & 63, wave = tid >> 6;
    const int wm = (wave >> 1) * 64, wn = (wave & 1) * 64;
    const int m0 = blockIdx.y * 128, n0 = blockIdx.x * 128;
    const int kBeg = blockIdx.z * 512;
    const int l15 = lane & 15, quad = lane >> 4;

    f32x4 acc[4][4];
#pragma unroll
    for (int i = 0; i < 4; i++)
#pragma unroll
        for (int j = 0; j < 4; j++) acc[i][j] = (f32x4){0.f, 0.f, 0.f, 0.f};

    const int r0 = tid >> 2, c0 = (tid & 3) * 8;

    for (int kk = kBeg; kk < kBeg + 512; kk += 32) {
        __syncthreads();
        cp16(A + (size_t)(m0 + r0) * 1024 + kk + c0,      As + r0 * 32 + c0);
        cp16(A + (size_t)(m0 + r0 + 64) * 1024 + kk + c0, As + (r0 + 64) * 32 + c0);
        cp16(B + (size_t)(n0 + r0) * 1024 + kk + c0,      Bs + r0 * 32 + c0);
        cp16(B + (size_t)(n0 + r0 + 64) * 1024 + kk + c0, Bs + (r0 + 64) * 32 + c0);
        __syncthreads();

        bf16x8 af[4], bfr[4];
#pragma unroll
        for (int i = 0; i < 4; i++)
            af[i] = *(const bf16x8*)(As + (wm + i * 16 + l15) * 32 + quad * 8);
#pragma unroll
        for (int j = 0; j < 4; j++)
            bfr[j] = *(const bf16x8*)(Bs + (wn + j * 16 + l15) * 32 + quad * 8);
#pragma unroll
        for (int i = 0; i < 4; i++)
#pragma unroll
            for (int j = 0; j < 4; j++)
                acc[i][j] = __builtin_amdgcn_mfma_f32_16x16x32_bf16(af[i], bfr[j], acc[i][j], 0, 0, 0);
    }

#pragma unroll
    for (int i = 0; i < 4; i++)
#pragma unroll
        for (int j = 0; j < 4; j++)
#pragma unroll
            for (int r = 0; r < 4; r++) {
                const int row = m0 + wm + i * 16 + quad * 4 + r;
                const int col = n0 + wn + j * 16 + l15;
                atomicAdd(&C[(size_t)row * 1024 + col], acc[i][j][r]);
            }
}

// Flash attention, causal, S^T formulation, XOR-swizzled LDS,
// single-barrier double-buffered K/V staging.
// Q (pre-scaled), K: [H][S][64] bf16. Vt: [H][64][S] bf16. Y: [S][DMODEL] bf16.
// Block = 4 waves, two mirrored 64-row q-tiles -> exactly 65 key-tiles/block.
__global__ __launch_bounds__(256) void attn(const u16* __restrict__ Q,
                                            const u16* __restrict__ Kh,
                                            const u16* __restrict__ Vt,
                                            u16* __restrict__ Y) {
    __shared__ __align__(16) u16 Ks[2][64 * 64];   // swizzled [key][dim]
    __shared__ __align__(16) u16 Vs[2][64 * 64];   // swizzled [dim][key]
    __shared__ __align__(16) u16 Pl[4][16 * 72];   // [q][key], stride 72
    const int h = blockIdx.y, bx = blockIdx.x;
    const int tid = threadIdx.x, lane = tid & 63, w = tid >> 6;
    const int l15 = lane & 15, quad = lane >> 4;
    const int swz = l15 & 7;

    const u16* Qp = Q + (size_t)h * S_LEN * 64;
    const u16* Kp = Kh + (size_t)h * S_LEN * 64;
    const u16* Vp = Vt + (size_t)h * 64 * S_LEN;

    // staging: lane tid owns LDS chunk tid*8; inverse-swizzle the global col
    const int srow = tid >> 3;
    const int scol = ((tid & 7) ^ (srow & 7)) * 8;

    for (int half = 0; half < 2; half++) {
        const int qa = (half == 0) ? 64 * bx : S_LEN - 64 * (bx + 1);
        const int nkt = (qa >> 6) + 1;
        const int qbase = qa + w * 16;
        const int qrow = qbase + l15;

        bf16x8 aq[2];
#pragma unroll
        for (int s = 0; s < 2; s++)
            aq[s] = *(const bf16x8*)(Qp + (size_t)(qbase + l15) * 64 + s * 32 + quad * 8);

        f32x4 o[4];
#pragma unroll
        for (int j = 0; j < 4; j++) o[j] = (f32x4){0.f, 0.f, 0.f, 0.f};
        float lrow = 0.f;

        __syncthreads();  // all waves done with previous half's buffers
        // prologue: stage tile 0 into buf 0
        cp16(Kp + (size_t)srow * 64 + scol,        Ks[0] + tid * 8);
        cp16(Kp + (size_t)(srow + 32) * 64 + scol, Ks[0] + tid * 8 + 2048);
        cp16(Vp + (size_t)srow * S_LEN + scol,        Vs[0] + tid * 8);
        cp16(Vp + (size_t)(srow + 32) * S_LEN + scol, Vs[0] + tid * 8 + 2048);

        int cur = 0;
        for (int kt = 0; kt < nkt; kt++) {
            __syncthreads();  // drains vmcnt(0): buf[cur] ready; buf[cur^1] reads done
            if (kt + 1 < nkt) {
                const int kn = (kt + 1) * 64;
                cp16(Kp + (size_t)(kn + srow) * 64 + scol,      Ks[cur ^ 1] + tid * 8);
                cp16(Kp + (size_t)(kn + srow + 32) * 64 + scol, Ks[cur ^ 1] + tid * 8 + 2048);
                cp16(Vp + (size_t)srow * S_LEN + kn + scol,        Vs[cur ^ 1] + tid * 8);
                cp16(Vp + (size_t)(srow + 32) * S_LEN + kn + scol, Vs[cur ^ 1] + tid * 8 + 2048);
            }
            const u16* K_ = Ks[cur];
            const u16* V_ = Vs[cur];
            const int kb = kt * 64;
            const bool boundary = (kt == nkt - 1);
#pragma unroll
            for (int t = 0; t < 4; t++) {
                // A-frag = K rows (m=key), swizzled read: all 32 banks
                const bf16x8 k0 = *(const bf16x8*)(K_ + (t * 16 + l15) * 64 + (quad ^ swz) * 8);
                const bf16x8 k1 = *(const bf16x8*)(K_ + (t * 16 + l15) * 64 + ((4 + quad) ^ swz) * 8);
                f32x4 c = (f32x4){0.f, 0.f, 0.f, 0.f};
                c = __builtin_amdgcn_mfma_f32_16x16x32_bf16(k0, aq[0], c, 0, 0, 0);
                c = __builtin_amdgcn_mfma_f32_16x16x32_bf16(k1, aq[1], c, 0, 0, 0);
                // S^T: lane holds keys kb+t*16+quad*4+r for q=qrow (Q pre-scaled)
                const int keyb = kb + t * 16 + quad * 4;
                float p[4];
#pragma unroll
                for (int r = 0; r < 4; r++) {
                    p[r] = exp2f(c[r]);
                    if (boundary && (keyb + r > qrow)) p[r] = 0.f;
                }
                lrow += (p[0] + p[1]) + (p[2] + p[3]);
                const u32 w0 = pkbf2(p[0], p[1]);
                const u32 w1 = pkbf2(p[2], p[3]);
                *(u64*)(&Pl[w][l15 * 72 + t * 16 + quad * 4]) = (u64)w0 | ((u64)w1 << 32);
            }
            // B-frag = P rows (n=q), contiguous 16B; stride 72 -> conflict-free
            const bf16x8 p0 = *(const bf16x8*)(&Pl[w][l15 * 72 + quad * 8]);
            const bf16x8 p1 = *(const bf16x8*)(&Pl[w][l15 * 72 + 32 + quad * 8]);
#pragma unroll
            for (int jj = 0; jj < 4; jj++) {
                // A-frag = Vt rows (m=dim), swizzled
                const bf16x8 v0 = *(const bf16x8*)(V_ + (jj * 16 + l15) * 64 + (quad ^ swz) * 8);
                const bf16x8 v1 = *(const bf16x8*)(V_ + (jj * 16 + l15) * 64 + ((4 + quad) ^ swz) * 8);
                o[jj] = __builtin_amdgcn_mfma_f32_16x16x32_bf16(v0, p0, o[jj], 0, 0, 0);
                o[jj] = __builtin_amdgcn_mfma_f32_16x16x32_bf16(v1, p1, o[jj], 0, 0, 0);
            }
            cur ^= 1;
        }

        // O^T layout: lane owns row q=qrow, dims jj*16+quad*4+r.
        lrow += __shfl_xor(lrow, 16);
        lrow += __shfl_xor(lrow, 32);
        const float inv = 1.f / lrow;
#pragma unroll
        for (int jj = 0; jj < 4; jj++) {
            const u32 w0 = pkbf2(o[jj][0] * inv, o[jj][1] * inv);
            const u32 w1 = pkbf2(o[jj][2] * inv, o[jj][3] * inv);
            *(u64*)(Y + (size_t)qrow * DMODEL + h * 64 + jj * 16 + quad * 4) =
                (u64)w0 | ((u64)w1 << 32);
        }
    }
}

extern "C" void kernel_launch(void* const* d_in, const int* in_sizes, int n_in,
                              void* d_out, int out_size, void* d_ws, size_t ws_size,
                              hipStream_t stream) {
    const float* x  = (const float*)d_in[0];
    const float* wq = (const float*)d_in[1];
    const float* wk = (const float*)d_in[2];
    const float* wv = (const float*)d_in[3];
    const float* wo = (const float*)d_in[4];
    float* out = (float*)d_out;

    u16* qh  = (u16*)d_ws;                            // 8 MB
    u16* kh  = qh + (size_t)S_LEN * DMODEL;           // 8 MB
    u16* vt  = kh + (size_t)S_LEN * DMODEL;           // 8 MB
    u16* xb  = vt + (size_t)S_LEN * DMODEL;           // 8 MB (x bf16, later y)
    u16* y   = xb;                                    // alias after QKV proj
    u16* wb3 = xb + (size_t)S_LEN * DMODEL;           // 6 MB ([wq;wk;wv], later wo)

    const dim3 blk(256);
    const int nx = S_LEN * DMODEL;   // 4M
    const int nw = DMODEL * DMODEL;  // 1M

    cvt_bf16<<<nx / 2048, blk, 0, stream>>>(x, xb, nx);
    cvt3_bf16<<<dim3(nw / 2048, 3), blk, 0, stream>>>(wq, wk, wv, wb3, nw);
    gemm_qkv<<<dim3(3 * DMODEL / 128, S_LEN / 128), blk, 0, stream>>>(xb, wb3, qh, kh, vt);
    attn<<<dim3(S_LEN / 128, NHEADS), blk, 0, stream>>>(qh, kh, vt, y);
    cvt_bf16<<<nw / 2048, blk, 0, stream>>>(wo, wb3, nw);
    hipMemsetAsync(out, 0, (size_t)S_LEN * DMODEL * sizeof(float), stream);
    gemm_out<<<dim3(DMODEL / 128, S_LEN / 128, 2), blk, 0, stream>>>(y, wb3, out);
}